// Round 10
// baseline (15.646 us; speedup 1.0000x reference)
//
#include <hip/hip_runtime.h>

// BagOfWords: out[b][v] = count of token v in docs[b][:] / SEQ
// docs: int32 [256, 2048], out: float32 [256, 32000]
//
// R10 = R8 with 2x grid oversubscription (generation pipelining).
// NCHUNK 4->8: 4000-bin chunks, 16 KB LDS, BLK=512. Residency stays
// 4 blocks/CU (thread-limited: 2048/512), but grid = 2048 = 2 generations.
// Gen-2 blocks launch as gen-1 blocks retire: their zero+scatter phases
// overlap the tail of gen-1's store burst -> HBM write pipe stays busy
// instead of idling during a single lockstep prologue (R8: grid ==
// residency meant one generation, write pipe idle ~40% of kernel).
// Zero-work is invariant (NCHUNK*CHUNK = VOCAB); extra token re-reads are
// L2/L3 hits (docs = 2 MB, chip-level L3).
//
// Kept (journal-proven): u32 bins (u16 regressed R5/R7), loads AFTER the
// zero barrier (hoists regressed R2/R3/R5/R9), natural block ids,
// nontemporal lane-consecutive 16B stores (R8 win).

#define VOCAB 32000
#define BATCH 256
#define SEQ   2048
#define NCHUNK 8
#define CHUNK (VOCAB / NCHUNK)   // 4000 bins -> 16 KB LDS
#define BLK   512

typedef float f32x4 __attribute__((ext_vector_type(4)));

__global__ __launch_bounds__(BLK) void bow_hist_kernel(
    const int* __restrict__ docs, float* __restrict__ out) {
    __shared__ unsigned int bins[CHUNK];

    const int wg   = blockIdx.x;          // 0..2047, natural mapping
    const int b    = wg >> 3;             // row index
    const int c    = wg & (NCHUNK - 1);   // vocab chunk
    const int base = c * CHUNK;
    const int tid  = threadIdx.x;

    // 1) zero the LDS histogram chunk (1000 uint4 -> 2 ragged iters)
    uint4* bins4 = reinterpret_cast<uint4*>(bins);
    for (int i = tid; i < CHUNK / 4; i += BLK) {
        bins4[i] = make_uint4(0u, 0u, 0u, 0u);
    }
    __syncthreads();

    // 2) scan the row: 512 int4 covers all 2048 tokens (1 per thread)
    const int4* row4 = reinterpret_cast<const int4*>(docs + (size_t)b * SEQ);
    int4 t = row4[tid];
    int r;
    r = t.x - base; if ((unsigned)r < (unsigned)CHUNK) atomicAdd(&bins[r], 1u);
    r = t.y - base; if ((unsigned)r < (unsigned)CHUNK) atomicAdd(&bins[r], 1u);
    r = t.z - base; if ((unsigned)r < (unsigned)CHUNK) atomicAdd(&bins[r], 1u);
    r = t.w - base; if ((unsigned)r < (unsigned)CHUNK) atomicAdd(&bins[r], 1u);
    __syncthreads();

    // 3) stream the chunk out, normalized; lane-consecutive nontemporal
    //    16B stores (2 ragged iters)
    float* orow = out + (size_t)b * VOCAB + base;
    const float inv = 1.0f / (float)SEQ;   // exact power of two
    for (int i = tid; i < CHUNK / 4; i += BLK) {
        uint4 u = bins4[i];
        f32x4 v;
        v.x = (float)u.x * inv;
        v.y = (float)u.y * inv;
        v.z = (float)u.z * inv;
        v.w = (float)u.w * inv;
        __builtin_nontemporal_store(v, reinterpret_cast<f32x4*>(orow) + i);
    }
}

extern "C" void kernel_launch(void* const* d_in, const int* in_sizes, int n_in,
                              void* d_out, int out_size, void* d_ws, size_t ws_size,
                              hipStream_t stream) {
    const int* docs = (const int*)d_in[0];
    float* out = (float*)d_out;
    bow_hist_kernel<<<dim3(BATCH * NCHUNK), dim3(BLK), 0, stream>>>(docs, out);
}